// Round 1
// baseline (121.650 us; speedup 1.0000x reference)
//
#include <hip/hip_runtime.h>

// Problem constants (match reference)
#define N_IMG 50331648    // 1024*3*128*128
#define BATCH 1024
#define DLAT  128

// ws layout: acc[0]=bce_sum, acc[1]=kl_sum, acc[2]=trip_sum (doubles)

__global__ __launch_bounds__(256) void bce_reduce_kernel(
    const float* __restrict__ real,
    const float* __restrict__ fake,
    double* __restrict__ acc)
{
    const float4* __restrict__ r4 = reinterpret_cast<const float4*>(real);
    const float4* __restrict__ f4 = reinterpret_cast<const float4*>(fake);
    const int n4 = N_IMG / 4;
    const int stride = gridDim.x * blockDim.x;

    float s = 0.0f;
    for (int i = blockIdx.x * blockDim.x + threadIdx.x; i < n4; i += stride) {
        float4 r = r4[i];
        float4 f = f4[i];
        s += r.x * __logf(f.x) + (1.0f - r.x) * __logf(1.0f - f.x);
        s += r.y * __logf(f.y) + (1.0f - r.y) * __logf(1.0f - f.y);
        s += r.z * __logf(f.z) + (1.0f - r.z) * __logf(1.0f - f.z);
        s += r.w * __logf(f.w) + (1.0f - r.w) * __logf(1.0f - f.w);
    }

    // wave-64 reduce
    #pragma unroll
    for (int o = 32; o > 0; o >>= 1) s += __shfl_down(s, o, 64);

    __shared__ float wsum[4];
    const int lane = threadIdx.x & 63;
    const int wid  = threadIdx.x >> 6;
    if (lane == 0) wsum[wid] = s;
    __syncthreads();
    if (threadIdx.x == 0) {
        float t = wsum[0] + wsum[1] + wsum[2] + wsum[3];
        atomicAdd(&acc[0], (double)t);
    }
}

__global__ __launch_bounds__(128) void latent_kernel(
    const float* __restrict__ mean, const float* __restrict__ logvar,
    const float* __restrict__ am,   const float* __restrict__ al,
    const float* __restrict__ pm,   const float* __restrict__ pl,
    const float* __restrict__ nm,   const float* __restrict__ nl,
    double* __restrict__ acc)
{
    const int b   = blockIdx.x;
    const int j   = threadIdx.x;      // 0..127 latent dim
    const int idx = b * DLAT + j;

    // VAE KL partial: 1 + logvar - mean^2 - exp(logvar)
    const float m  = mean[idx];
    const float lv = logvar[idx];
    const float kl_p = 1.0f + lv - m * m - expf(lv);

    const float amj = am[idx], alj = al[idx];
    const float pmj = pm[idx], plj = pl[idx];
    const float nmj = nm[idx], nlj = nl[idx];
    const float va  = expf(alj);

    // term_a + term_b = 2*log(vm) - la - lb + 2 + 0.5*(ma-mb)^2/vm
    // (since (va+vb)/vm == 4 and (mean_m-ma)^2 == (mean_m-mb)^2 == 0.25*(ma-mb)^2)
    // anchor-positive
    const float vp   = expf(plj);
    const float vm_p = 0.25f * (va + vp);
    const float dmp  = amj - pmj;
    const float s_ap = 2.0f * logf(vm_p) - alj - plj + 2.0f + 0.5f * dmp * dmp / vm_p;

    // anchor-negative
    const float vn   = expf(nlj);
    const float vm_n = 0.25f * (va + vn);
    const float dmn  = amj - nmj;
    const float s_an = 2.0f * logf(vm_n) - alj - nlj + 2.0f + 0.5f * dmn * dmn / vm_n;

    // block reduce three values (128 threads = 2 waves)
    float a = s_ap, c = s_an, k = kl_p;
    #pragma unroll
    for (int o = 32; o > 0; o >>= 1) {
        a += __shfl_down(a, o, 64);
        c += __shfl_down(c, o, 64);
        k += __shfl_down(k, o, 64);
    }
    __shared__ float red[2][3];
    const int lane = threadIdx.x & 63;
    const int wid  = threadIdx.x >> 6;
    if (lane == 0) { red[wid][0] = a; red[wid][1] = c; red[wid][2] = k; }
    __syncthreads();
    if (threadIdx.x == 0) {
        const float S_ap = red[0][0] + red[1][0];
        const float S_an = red[0][1] + red[1][1];
        const float S_kl = red[0][2] + red[1][2];
        // js = 0.25 * S ; d = -js ; prob = softmax([d_ap,d_an])[0]
        //      = 1 / (1 + exp(d_an - d_ap)) = 1 / (1 + exp(js_ap - js_an))
        const float js_ap = 0.25f * S_ap;
        const float js_an = 0.25f * S_an;
        const float prob  = 1.0f / (1.0f + expf(js_ap - js_an));
        atomicAdd(&acc[1], (double)S_kl);
        atomicAdd(&acc[2], (double)prob);
    }
}

__global__ void finalize_kernel(const double* __restrict__ acc, float* __restrict__ out)
{
    if (threadIdx.x == 0 && blockIdx.x == 0) {
        const double recon   = -(acc[0] / (double)N_IMG);
        const double kl      = -0.5 * (acc[1] / (double)(BATCH * DLAT));
        const double triplet = -(acc[2] / (double)BATCH);
        out[0] = (float)(recon + kl + triplet);  // final_loss
        out[1] = (float)triplet;                 // triplet_error
        out[2] = (float)recon;                   // recon_error
        out[3] = (float)kl;                      // kl_error
    }
}

extern "C" void kernel_launch(void* const* d_in, const int* in_sizes, int n_in,
                              void* d_out, int out_size, void* d_ws, size_t ws_size,
                              hipStream_t stream)
{
    const float* real = (const float*)d_in[0];
    const float* fake = (const float*)d_in[1];
    const float* mean = (const float*)d_in[2];
    const float* logv = (const float*)d_in[3];
    const float* am   = (const float*)d_in[4];
    const float* al   = (const float*)d_in[5];
    const float* pm   = (const float*)d_in[6];
    const float* pl   = (const float*)d_in[7];
    const float* nm   = (const float*)d_in[8];
    const float* nl   = (const float*)d_in[9];
    float*  out = (float*)d_out;
    double* acc = (double*)d_ws;

    hipMemsetAsync(acc, 0, 3 * sizeof(double), stream);

    // BCE: 402.7 MB streaming read, memory-bound. 2048 blocks x 256 thr,
    // grid-stride float4 (24 iters/thread).
    bce_reduce_kernel<<<2048, 256, 0, stream>>>(real, fake, &acc[0]);

    // Latent: one block per batch row.
    latent_kernel<<<BATCH, DLAT, 0, stream>>>(mean, logv, am, al, pm, pl, nm, nl, acc);

    finalize_kernel<<<1, 64, 0, stream>>>(acc, out);
}

// Round 2
// 116.230 us; speedup vs baseline: 1.0466x; 1.0466x over previous
//
#include <hip/hip_runtime.h>

// Problem constants (match reference)
#define N_IMG 50331648    // 1024*3*128*128
#define BATCH 1024
#define DLAT  128
#define LN2   0.69314718055994530942

// ws layout: acc[0]=bce_sum (in log2 domain), acc[1]=kl_sum, acc[2]=trip_sum (doubles)

// One element of BCE in log2 domain: r*log2(f) + (1-r)*log2(1-f)
//   = lg + r*(lf - lg)  where lf=log2(f), lg=log2(1-f)
// __log2f -> __ocml_native_log2_f32 -> single v_log_f32.
__device__ __forceinline__ float bce2(float r, float f) {
    const float lf = __log2f(f);
    const float lg = __log2f(1.0f - f);
    return lg + r * (lf - lg);
}

__global__ __launch_bounds__(256) void bce_reduce_kernel(
    const float* __restrict__ real,
    const float* __restrict__ fake,
    double* __restrict__ acc)
{
    const float4* __restrict__ r4 = reinterpret_cast<const float4*>(real);
    const float4* __restrict__ f4 = reinterpret_cast<const float4*>(fake);
    // n4 = 12,582,912 float4 pairs; 524,288 threads -> 24 float4/thread, 2 per iter.
    const int stride = gridDim.x * blockDim.x;          // 524288
    int i = blockIdx.x * blockDim.x + threadIdx.x;

    float s0 = 0.0f, s1 = 0.0f;
    #pragma unroll 3
    for (int it = 0; it < 12; ++it, i += 2 * stride) {
        // hoist all 4 loads (4KB/wave in flight) before compute
        const float4 ra = r4[i];
        const float4 fa = f4[i];
        const float4 rb = r4[i + stride];
        const float4 fb = f4[i + stride];
        s0 += bce2(ra.x, fa.x);
        s1 += bce2(ra.y, fa.y);
        s0 += bce2(ra.z, fa.z);
        s1 += bce2(ra.w, fa.w);
        s0 += bce2(rb.x, fb.x);
        s1 += bce2(rb.y, fb.y);
        s0 += bce2(rb.z, fb.z);
        s1 += bce2(rb.w, fb.w);
    }
    float s = s0 + s1;

    // wave-64 reduce
    #pragma unroll
    for (int o = 32; o > 0; o >>= 1) s += __shfl_down(s, o, 64);

    __shared__ float wsum[4];
    const int lane = threadIdx.x & 63;
    const int wid  = threadIdx.x >> 6;
    if (lane == 0) wsum[wid] = s;
    __syncthreads();
    if (threadIdx.x == 0) {
        float t = wsum[0] + wsum[1] + wsum[2] + wsum[3];
        atomicAdd(&acc[0], (double)t);
    }
}

__global__ __launch_bounds__(128) void latent_kernel(
    const float* __restrict__ mean, const float* __restrict__ logvar,
    const float* __restrict__ am,   const float* __restrict__ al,
    const float* __restrict__ pm,   const float* __restrict__ pl,
    const float* __restrict__ nm,   const float* __restrict__ nl,
    double* __restrict__ acc)
{
    const int b   = blockIdx.x;
    const int j   = threadIdx.x;      // 0..127 latent dim
    const int idx = b * DLAT + j;

    // VAE KL partial: 1 + logvar - mean^2 - exp(logvar)
    const float m  = mean[idx];
    const float lv = logvar[idx];
    const float kl_p = 1.0f + lv - m * m - expf(lv);

    const float amj = am[idx], alj = al[idx];
    const float pmj = pm[idx], plj = pl[idx];
    const float nmj = nm[idx], nlj = nl[idx];
    const float va  = expf(alj);

    // term_a + term_b = 2*log(vm) - la - lb + 2 + 0.5*(ma-mb)^2/vm
    // (since (va+vb)/vm == 4 and (mean_m-ma)^2 == (mean_m-mb)^2 == 0.25*(ma-mb)^2)
    const float vp   = expf(plj);
    const float vm_p = 0.25f * (va + vp);
    const float dmp  = amj - pmj;
    const float s_ap = 2.0f * logf(vm_p) - alj - plj + 2.0f + 0.5f * dmp * dmp / vm_p;

    const float vn   = expf(nlj);
    const float vm_n = 0.25f * (va + vn);
    const float dmn  = amj - nmj;
    const float s_an = 2.0f * logf(vm_n) - alj - nlj + 2.0f + 0.5f * dmn * dmn / vm_n;

    // block reduce three values (128 threads = 2 waves)
    float a = s_ap, c = s_an, k = kl_p;
    #pragma unroll
    for (int o = 32; o > 0; o >>= 1) {
        a += __shfl_down(a, o, 64);
        c += __shfl_down(c, o, 64);
        k += __shfl_down(k, o, 64);
    }
    __shared__ float red[2][3];
    const int lane = threadIdx.x & 63;
    const int wid  = threadIdx.x >> 6;
    if (lane == 0) { red[wid][0] = a; red[wid][1] = c; red[wid][2] = k; }
    __syncthreads();
    if (threadIdx.x == 0) {
        const float S_ap = red[0][0] + red[1][0];
        const float S_an = red[0][1] + red[1][1];
        const float S_kl = red[0][2] + red[1][2];
        // prob = softmax([-js_ap, -js_an])[0] = 1/(1+exp(js_ap - js_an)), js = 0.25*S
        const float js_ap = 0.25f * S_ap;
        const float js_an = 0.25f * S_an;
        const float prob  = 1.0f / (1.0f + expf(js_ap - js_an));
        atomicAdd(&acc[1], (double)S_kl);
        atomicAdd(&acc[2], (double)prob);
    }
}

__global__ void finalize_kernel(const double* __restrict__ acc, float* __restrict__ out)
{
    if (threadIdx.x == 0 && blockIdx.x == 0) {
        const double recon   = -(LN2 * acc[0] / (double)N_IMG);   // log2 -> ln
        const double kl      = -0.5 * (acc[1] / (double)(BATCH * DLAT));
        const double triplet = -(acc[2] / (double)BATCH);
        out[0] = (float)(recon + kl + triplet);  // final_loss
        out[1] = (float)triplet;                 // triplet_error
        out[2] = (float)recon;                   // recon_error
        out[3] = (float)kl;                      // kl_error
    }
}

extern "C" void kernel_launch(void* const* d_in, const int* in_sizes, int n_in,
                              void* d_out, int out_size, void* d_ws, size_t ws_size,
                              hipStream_t stream)
{
    const float* real = (const float*)d_in[0];
    const float* fake = (const float*)d_in[1];
    const float* mean = (const float*)d_in[2];
    const float* logv = (const float*)d_in[3];
    const float* am   = (const float*)d_in[4];
    const float* al   = (const float*)d_in[5];
    const float* pm   = (const float*)d_in[6];
    const float* pl   = (const float*)d_in[7];
    const float* nm   = (const float*)d_in[8];
    const float* nl   = (const float*)d_in[9];
    float*  out = (float*)d_out;
    double* acc = (double*)d_ws;

    hipMemsetAsync(acc, 0, 3 * sizeof(double), stream);

    bce_reduce_kernel<<<2048, 256, 0, stream>>>(real, fake, &acc[0]);
    latent_kernel<<<BATCH, DLAT, 0, stream>>>(mean, logv, am, al, pm, pl, nm, nl, acc);
    finalize_kernel<<<1, 64, 0, stream>>>(acc, out);
}